// Round 2
// baseline (197.439 us; speedup 1.0000x reference)
//
#include <hip/hip_runtime.h>
#include <math.h>

// Problem constants (from reference):
//   N=32, C=1, H=512, W=1024 -> HW = 524288 per batch row
//   SAMPLE_NUM = 5000 pairs per row -> 160000 pairs total
//   SIGMA = 0.03, ALPHA = 1.0, EPS = 1e-6, LOSS_WEIGHT = 1.0
#define SAMPLE_NUM 5000
#define HWSZ (512 * 1024)
#define SIGMA_F 0.03f
#define EPS_F 1e-6f

// ws layout (16 bytes, zeroed via hipMemsetAsync each launch):
//   ws[0] = equal_loss sum (float)
//   ws[1] = unequal_loss sum (float)
//   ws[2] = valid_samples count (float)
//   ws[3] = done-block ticket counter (uint32)
__global__ void __launch_bounds__(256)
ranking_loss_kernel(const float* __restrict__ pred,
                    const float* __restrict__ targ,
                    const void* __restrict__ mask_raw,
                    const int* __restrict__ idxA,
                    const int* __restrict__ idxB,
                    float* __restrict__ out,
                    float* __restrict__ ws,
                    int total) {
  const float hi = 1.0f + SIGMA_F;
  const float lo = 1.0f / (1.0f + SIGMA_F);

  // --- Mask layout detection (thread-uniform) ---
  // If the harness stored the bool mask as int32, every word is 0 or 1.
  // If it stored 1-byte bools, a uint32 view packs 4 bools -> value > 1
  // with P = 7/8 per word. Scan 32 words: misdetect P = 8^-32 ~ 1e-29.
  const unsigned int* mw = (const unsigned int*)mask_raw;
  bool mask_is_i32 = true;
  #pragma unroll
  for (int w = 0; w < 32; ++w) {
    if (mw[w] > 1u) mask_is_i32 = false;
  }
  const unsigned char* m8 = (const unsigned char*)mask_raw;
  const int* m32 = (const int*)mask_raw;

  float eq_sum = 0.0f, uneq_sum = 0.0f, valid = 0.0f;

  for (int i = blockIdx.x * blockDim.x + threadIdx.x; i < total;
       i += gridDim.x * blockDim.x) {
    const int n = i / SAMPLE_NUM;                    // batch row
    const long long base = (long long)n * HWSZ;
    const int a = idxA[i];
    const int b = idxB[i];

    int ma, mb;
    if (mask_is_i32) {
      ma = m32[base + a];
      mb = m32[base + b];
    } else {
      ma = (int)m8[base + a];
      mb = (int)m8[base + b];
    }

    if (ma && mb) {
      valid += 1.0f;
      const float tA = targ[base + a];
      const float tB = targ[base + b];
      const float ratio = tA / (tB + EPS_F);
      const float iA = pred[base + a];
      const float iB = pred[base + b];
      if (ratio < hi && ratio > lo) {
        const float d = iA - iB;
        eq_sum += d * d;           // ALPHA == 1.0
      } else {
        const float label = (ratio >= hi) ? 1.0f : -1.0f;
        const float x = (iB - iA) * label;
        // log1p(exp(x)); for x > 20, log1p(exp(x)) == x to fp32 precision.
        const float u = (x > 20.0f) ? x : log1pf(expf(x));
        uneq_sum += u;
      }
    }
  }

  // Wave-64 shuffle reduction
  #pragma unroll
  for (int off = 32; off > 0; off >>= 1) {
    eq_sum   += __shfl_down(eq_sum, off, 64);
    uneq_sum += __shfl_down(uneq_sum, off, 64);
    valid    += __shfl_down(valid, off, 64);
  }

  __shared__ float s_eq[4], s_un[4], s_va[4];
  const int lane = threadIdx.x & 63;
  const int wave = threadIdx.x >> 6;
  if (lane == 0) {
    s_eq[wave] = eq_sum;
    s_un[wave] = uneq_sum;
    s_va[wave] = valid;
  }
  __syncthreads();

  if (threadIdx.x == 0) {
    float e = 0.0f, u = 0.0f, v = 0.0f;
    const int nwaves = blockDim.x >> 6;
    for (int w = 0; w < nwaves; ++w) {
      e += s_eq[w];
      u += s_un[w];
      v += s_va[w];
    }
    atomicAdd(&ws[0], e);
    atomicAdd(&ws[1], u);
    atomicAdd(&ws[2], v);
    __threadfence();  // make sums visible device-wide before ticket
    const unsigned int ticket =
        atomicAdd((unsigned int*)&ws[3], 1u);
    if (ticket == gridDim.x - 1) {
      // Last block: read back via atomic RMW (device-scope coherent read,
      // safe across non-coherent per-XCD L2s).
      const float eqs = atomicAdd(&ws[0], 0.0f);
      const float uns = atomicAdd(&ws[1], 0.0f);
      const float vas = atomicAdd(&ws[2], 0.0f);
      out[0] = (eqs + uns) / (vas + EPS_F);  // ALPHA=1, LOSS_WEIGHT=1
    }
  }
}

extern "C" void kernel_launch(void* const* d_in, const int* in_sizes, int n_in,
                              void* d_out, int out_size, void* d_ws,
                              size_t ws_size, hipStream_t stream) {
  const float* pred = (const float*)d_in[0];
  const float* targ = (const float*)d_in[1];
  const void* mask = d_in[2];  // bool array; layout detected on device
  const int* idxA = (const int*)d_in[3];
  const int* idxB = (const int*)d_in[4];
  float* out = (float*)d_out;
  float* ws = (float*)d_ws;

  const int total = in_sizes[3];  // N * SAMPLE_NUM = 160000

  // Zero the 4-word accumulator block (ws is re-poisoned to 0xAA each launch).
  hipMemsetAsync(d_ws, 0, 4 * sizeof(float), stream);

  const int block = 256;
  const int grid = (total + block - 1) / block;  // 625 blocks
  ranking_loss_kernel<<<grid, block, 0, stream>>>(pred, targ, mask, idxA, idxB,
                                                  out, ws, total);
}